// Round 1
// baseline (702.090 us; speedup 1.0000x reference)
//
#include <hip/hip_runtime.h>

#define S_ 4
#define C_ 256
#define CE_ 128
#define KD_ 128
#define HW_ 1024
#define T_ 8
#define M_ 8192
#define NSPLIT 4
#define NEGINF -3.0e38f

// ---------------- workspace layout (float offsets) ----------------
// P_self : 4*1024*128   = 524288
// A      : 4*1024*1024  = 4194304
// Z      : 4*256*1024   = 1048576
// Zn     : 4*256*1024   = 1048576
// Qc     : 4*1024*128   = 524288
// Kc     : 4*8192*128   = 4194304
// Opart  : 4*4*1024*128 = 2097152
// mpart  : 4*4*1024     = 16384
// lpart  : 4*4*1024     = 16384
#define O_PSELF 0u
#define O_A     524288u
#define O_Z     4718592u
#define O_ZN    5767168u
#define O_QC    6815744u
#define O_KC    7340032u
#define O_OPART 11534336u
#define O_MPART 13631488u
#define O_LPART 13647872u
// total 13664256 floats = ~54.7 MB of d_ws

// ============================================================================
// P[s][r][d] = l2norm_d( X[r,s,:] @ W^T + b ), rows r = t*HW+l,
// src layout: ((t*S+s)*C + ch)*HW + l   (works for tgt (T=1), memory (T=8), Zn (T=1))
// out layout: ((s*R + r)*128 + d)
// ============================================================================
__global__ __launch_bounds__(256)
void proj_norm_kernel(const float* __restrict__ src, const float* __restrict__ Wm,
                      const float* __restrict__ bias, float* __restrict__ out, int R)
{
    __shared__ float Xs[32][65];
    __shared__ float Ws[32][129];
    const int s  = blockIdx.y;
    const int r0 = blockIdx.x * 64;
    const int t  = r0 >> 10;
    const int l0 = r0 & 1023;
    const int tid = threadIdx.x;
    const int tx = tid & 15, ty = tid >> 4;
    const float* xb = src + ((size_t)(t * S_ + s) * C_) * HW_ + l0;

    float acc[4][8];
#pragma unroll
    for (int i = 0; i < 4; ++i)
#pragma unroll
        for (int j = 0; j < 8; ++j) acc[i][j] = 0.f;

    for (int c0 = 0; c0 < C_; c0 += 32) {
#pragma unroll
        for (int j = 0; j < 8; ++j) {
            int idx = tid + j * 256;
            Xs[idx >> 6][idx & 63] = xb[(size_t)(c0 + (idx >> 6)) * HW_ + (idx & 63)];
        }
#pragma unroll
        for (int j = 0; j < 16; ++j) {
            int idx = tid + j * 256;
            Ws[idx & 31][idx >> 5] = Wm[(idx >> 5) * C_ + c0 + (idx & 31)];
        }
        __syncthreads();
        for (int cc = 0; cc < 32; ++cc) {
            float xv[4], wv[8];
#pragma unroll
            for (int i = 0; i < 4; ++i) xv[i] = Xs[cc][ty * 4 + i];
#pragma unroll
            for (int j = 0; j < 8; ++j) wv[j] = Ws[cc][tx * 8 + j];
#pragma unroll
            for (int i = 0; i < 4; ++i)
#pragma unroll
                for (int j = 0; j < 8; ++j) acc[i][j] = fmaf(xv[i], wv[j], acc[i][j]);
        }
        __syncthreads();
    }

    float bv[8];
#pragma unroll
    for (int j = 0; j < 8; ++j) bv[j] = bias[tx * 8 + j];

#pragma unroll
    for (int i = 0; i < 4; ++i) {
        float ss = 0.f;
#pragma unroll
        for (int j = 0; j < 8; ++j) {
            acc[i][j] += bv[j];
            ss = fmaf(acc[i][j], acc[i][j], ss);
        }
#pragma unroll
        for (int m = 1; m < 16; m <<= 1) ss += __shfl_xor(ss, m);
        float sc = 1.f / fmaxf(sqrtf(ss), 1e-12f);
        int r = r0 + ty * 4 + i;
        float* op = out + ((size_t)s * R + r) * KD_ + tx * 8;
#pragma unroll
        for (int j = 0; j < 8; ++j) op[j] = acc[i][j] * sc;
    }
}

// ============================================================================
// A[s][q][k] = 30 * dot128(P[s][q], P[s][k])
// ============================================================================
__global__ __launch_bounds__(256)
void self_scores_kernel(const float* __restrict__ P, float* __restrict__ A)
{
    __shared__ float Qs[64][33];
    __shared__ float Ks[64][33];
    const int s = blockIdx.z;
    const int q0 = blockIdx.x * 64, k0 = blockIdx.y * 64;
    const int tid = threadIdx.x;
    const int tx = tid & 15, ty = tid >> 4;
    const float* Pb = P + (size_t)s * HW_ * KD_;

    float acc[4][4];
#pragma unroll
    for (int i = 0; i < 4; ++i)
#pragma unroll
        for (int j = 0; j < 4; ++j) acc[i][j] = 0.f;

    for (int d0 = 0; d0 < KD_; d0 += 32) {
#pragma unroll
        for (int j = 0; j < 8; ++j) {
            int idx = tid + j * 256;
            int r = idx >> 5, dd = idx & 31;
            Qs[r][dd] = Pb[(size_t)(q0 + r) * KD_ + d0 + dd];
            Ks[r][dd] = Pb[(size_t)(k0 + r) * KD_ + d0 + dd];
        }
        __syncthreads();
        for (int dd = 0; dd < 32; ++dd) {
            float qv[4], kv[4];
#pragma unroll
            for (int i = 0; i < 4; ++i) qv[i] = Qs[ty * 4 + i][dd];
#pragma unroll
            for (int j = 0; j < 4; ++j) kv[j] = Ks[tx * 4 + j][dd];
#pragma unroll
            for (int i = 0; i < 4; ++i)
#pragma unroll
                for (int j = 0; j < 4; ++j) acc[i][j] = fmaf(qv[i], kv[j], acc[i][j]);
        }
        __syncthreads();
    }
#pragma unroll
    for (int i = 0; i < 4; ++i)
#pragma unroll
        for (int j = 0; j < 4; ++j)
            A[((size_t)s * HW_ + q0 + ty * 4 + i) * HW_ + k0 + tx * 4 + j] = acc[i][j] * 30.0f;
}

// ============================================================================
// in-place row softmax over 1024 cols (4096 rows)
// ============================================================================
__global__ __launch_bounds__(256)
void softmax_kernel(float* __restrict__ A)
{
    __shared__ float red[4];
    __shared__ float red2[4];
    float* p = A + (size_t)blockIdx.x * HW_;
    const int tid = threadIdx.x;
    float4 x = ((float4*)p)[tid];
    float mx = fmaxf(fmaxf(x.x, x.y), fmaxf(x.z, x.w));
#pragma unroll
    for (int m = 1; m < 64; m <<= 1) mx = fmaxf(mx, __shfl_xor(mx, m));
    if ((tid & 63) == 0) red[tid >> 6] = mx;
    __syncthreads();
    mx = fmaxf(fmaxf(red[0], red[1]), fmaxf(red[2], red[3]));
    x.x = expf(x.x - mx); x.y = expf(x.y - mx);
    x.z = expf(x.z - mx); x.w = expf(x.w - mx);
    float sm = x.x + x.y + x.z + x.w;
#pragma unroll
    for (int m = 1; m < 64; m <<= 1) sm += __shfl_xor(sm, m);
    if ((tid & 63) == 0) red2[tid >> 6] = sm;
    __syncthreads();
    sm = red2[0] + red2[1] + red2[2] + red2[3];
    float inv = 1.f / sm;
    x.x *= inv; x.y *= inv; x.z *= inv; x.w *= inv;
    ((float4*)p)[tid] = x;
}

// ============================================================================
// Z[s][ch][q] = X[s][ch][q] + sum_k A[s][q][k] * X[s][ch][k]
// ============================================================================
__global__ __launch_bounds__(256)
void self_pv_kernel(const float* __restrict__ A, const float* __restrict__ X,
                    float* __restrict__ Z)
{
    __shared__ float As[64][33];
    __shared__ float Vs[32][65];
    const int s = blockIdx.z;
    const int q0 = blockIdx.x * 64;
    const int c0 = blockIdx.y * 64;
    const int tid = threadIdx.x;
    const int tx = tid & 15, ty = tid >> 4;
    const float* Ab = A + (size_t)s * HW_ * HW_;
    const float* Xb = X + (size_t)s * C_ * HW_;

    float acc[4][4];
#pragma unroll
    for (int i = 0; i < 4; ++i)
#pragma unroll
        for (int j = 0; j < 4; ++j) acc[i][j] = 0.f;

    for (int k0 = 0; k0 < HW_; k0 += 32) {
#pragma unroll
        for (int j = 0; j < 8; ++j) {
            int idx = tid + j * 256;
            int r = idx >> 5, kk = idx & 31;
            As[r][kk] = Ab[(size_t)(q0 + r) * HW_ + k0 + kk];
        }
#pragma unroll
        for (int j = 0; j < 8; ++j) {
            int idx = tid + j * 256;
            int ch = idx >> 5, kk = idx & 31;
            Vs[kk][ch] = Xb[(size_t)(c0 + ch) * HW_ + k0 + kk];
        }
        __syncthreads();
        for (int kk = 0; kk < 32; ++kk) {
            float av[4], vv[4];
#pragma unroll
            for (int i = 0; i < 4; ++i) av[i] = As[ty * 4 + i][kk];
#pragma unroll
            for (int j = 0; j < 4; ++j) vv[j] = Vs[kk][tx * 4 + j];
#pragma unroll
            for (int i = 0; i < 4; ++i)
#pragma unroll
                for (int j = 0; j < 4; ++j) acc[i][j] = fmaf(av[i], vv[j], acc[i][j]);
        }
        __syncthreads();
    }
#pragma unroll
    for (int i = 0; i < 4; ++i)
#pragma unroll
        for (int j = 0; j < 4; ++j) {
            int q = q0 + ty * 4 + i, ch = c0 + tx * 4 + j;
            size_t a = (size_t)(s * C_ + ch) * HW_ + q;
            Z[a] = acc[i][j] + X[a];
        }
}

// ============================================================================
// InstanceNorm over spatial (1024) per (s,ch) row; Z,Zn layout (s,ch,l)
// ============================================================================
__global__ __launch_bounds__(256)
void inorm_kernel(const float* __restrict__ Z, float* __restrict__ Zn)
{
    __shared__ float red[4];
    __shared__ float red2[4];
    const float* p = Z + (size_t)blockIdx.x * HW_;
    float* q = Zn + (size_t)blockIdx.x * HW_;
    const int tid = threadIdx.x;
    float4 x = ((const float4*)p)[tid];
    float sm = x.x + x.y + x.z + x.w;
#pragma unroll
    for (int m = 1; m < 64; m <<= 1) sm += __shfl_xor(sm, m);
    if ((tid & 63) == 0) red[tid >> 6] = sm;
    __syncthreads();
    float mu = (red[0] + red[1] + red[2] + red[3]) * (1.f / 1024.f);
    float dx0 = x.x - mu, dx1 = x.y - mu, dx2 = x.z - mu, dx3 = x.w - mu;
    float ss = dx0 * dx0 + dx1 * dx1 + dx2 * dx2 + dx3 * dx3;
#pragma unroll
    for (int m = 1; m < 64; m <<= 1) ss += __shfl_xor(ss, m);
    if ((tid & 63) == 0) red2[tid >> 6] = ss;
    __syncthreads();
    float var = (red2[0] + red2[1] + red2[2] + red2[3]) * (1.f / 1024.f);
    float inv = 1.f / sqrtf(var + 1e-5f);
    float4 o;
    o.x = dx0 * inv; o.y = dx1 * inv; o.z = dx2 * inv; o.w = dx3 * inv;
    ((float4*)q)[tid] = o;
}

// ============================================================================
// Flash cross-attention partials. Block: (qtile 64, key-split, s), 512 thr.
// Opart[(split*S+s)][q][e] (unnormalized, relative to mrow), mpart/lpart.
// ============================================================================
__global__ __launch_bounds__(512)
void cross_flash_kernel(const float* __restrict__ Qc, const float* __restrict__ Kc,
                        const float* __restrict__ pe, float* __restrict__ Opart,
                        float* __restrict__ mpart, float* __restrict__ lpart)
{
    __shared__ float Qs[64][132];
    __shared__ float Ks[64][132];
    __shared__ float Vs[64][129];
    __shared__ float Ps[64][72];
    __shared__ float mrow[64], lrow[64], srow[64];

    const int qt = blockIdx.x, split = blockIdx.y, s = blockIdx.z;
    const int q0 = qt * 64;
    const int tid = threadIdx.x;

    // score-phase ids: rows {ty, ty+32}, cols {tx+16j}
    const int tx = tid & 15;
    const int ty = tid >> 4;      // 0..31
    // pv-phase ids: rows {rg+16r}, e = ex + 16j + 64*eb
    const int ex = tid & 15;
    const int rg = (tid >> 4) & 15;
    const int eb = tid >> 8;      // 0/1

#pragma unroll
    for (int j = 0; j < 16; ++j) {
        int idx = tid + j * 512;
        int r = idx >> 7, d = idx & 127;
        Qs[r][d] = Qc[((size_t)s * HW_ + q0 + r) * KD_ + d];
    }
    if (tid < 64) { mrow[tid] = NEGINF; lrow[tid] = 0.f; }

    float acc[4][4];
#pragma unroll
    for (int r = 0; r < 4; ++r)
#pragma unroll
        for (int j = 0; j < 4; ++j) acc[r][j] = 0.f;

    __syncthreads();

    const int kbase = split * (M_ / NSPLIT);
    for (int kt = 0; kt < (M_ / NSPLIT) / 64; ++kt) {
        const int k0 = kbase + kt * 64;
        const int tt = k0 >> 10, ll = k0 & 1023;
#pragma unroll
        for (int j = 0; j < 16; ++j) {
            int idx = tid + j * 512;
            int r = idx >> 7, d = idx & 127;
            Ks[r][d] = Kc[((size_t)s * M_ + k0 + r) * KD_ + d];
        }
#pragma unroll
        for (int j = 0; j < 16; ++j) {
            int idx = tid + j * 512;
            int kk = idx & 63, e = idx >> 6;
            Vs[kk][e] = pe[((size_t)(tt * S_ + s) * CE_ + e) * HW_ + ll + kk];
        }
        __syncthreads();

        // ---- scores: 2 rows x 4 cols per thread ----
        float sc0[4] = {0.f, 0.f, 0.f, 0.f};
        float sc1[4] = {0.f, 0.f, 0.f, 0.f};
        for (int d0 = 0; d0 < KD_; d0 += 4) {
            float4 qa = *(const float4*)&Qs[ty][d0];
            float4 qb = *(const float4*)&Qs[ty + 32][d0];
#pragma unroll
            for (int j = 0; j < 4; ++j) {
                float4 kv = *(const float4*)&Ks[tx + 16 * j][d0];
                sc0[j] = fmaf(qa.x, kv.x, fmaf(qa.y, kv.y, fmaf(qa.z, kv.z, fmaf(qa.w, kv.w, sc0[j]))));
                sc1[j] = fmaf(qb.x, kv.x, fmaf(qb.y, kv.y, fmaf(qb.z, kv.z, fmaf(qb.w, kv.w, sc1[j]))));
            }
        }
        float mx0 = NEGINF, mx1 = NEGINF;
#pragma unroll
        for (int j = 0; j < 4; ++j) {
            sc0[j] *= 30.0f; sc1[j] *= 30.0f;
            mx0 = fmaxf(mx0, sc0[j]); mx1 = fmaxf(mx1, sc1[j]);
        }
#pragma unroll
        for (int m = 1; m < 16; m <<= 1) {
            mx0 = fmaxf(mx0, __shfl_xor(mx0, m));
            mx1 = fmaxf(mx1, __shfl_xor(mx1, m));
        }
        float mo0 = mrow[ty], mo1 = mrow[ty + 32];
        float mn0 = fmaxf(mo0, mx0), mn1 = fmaxf(mo1, mx1);
        float al0 = expf(mo0 - mn0), al1 = expf(mo1 - mn1);
        float ls0 = 0.f, ls1 = 0.f;
#pragma unroll
        for (int j = 0; j < 4; ++j) {
            float p0 = expf(sc0[j] - mn0);
            float p1 = expf(sc1[j] - mn1);
            Ps[ty][tx + 16 * j] = p0;
            Ps[ty + 32][tx + 16 * j] = p1;
            ls0 += p0; ls1 += p1;
        }
#pragma unroll
        for (int m = 1; m < 16; m <<= 1) {
            ls0 += __shfl_xor(ls0, m);
            ls1 += __shfl_xor(ls1, m);
        }
        if (tx == 0) {
            mrow[ty] = mn0; mrow[ty + 32] = mn1;
            lrow[ty] = lrow[ty] * al0 + ls0;
            lrow[ty + 32] = lrow[ty + 32] * al1 + ls1;
            srow[ty] = al0; srow[ty + 32] = al1;
        }
        __syncthreads();

        // ---- PV: 4 rows x 4 e per thread ----
#pragma unroll
        for (int r = 0; r < 4; ++r) {
            float sr = srow[rg + 16 * r];
#pragma unroll
            for (int j = 0; j < 4; ++j) acc[r][j] *= sr;
        }
#pragma unroll 4
        for (int kk = 0; kk < 64; ++kk) {
            float pr[4], vv[4];
#pragma unroll
            for (int r = 0; r < 4; ++r) pr[r] = Ps[rg + 16 * r][kk];
#pragma unroll
            for (int j = 0; j < 4; ++j) vv[j] = Vs[kk][ex + 16 * j + 64 * eb];
#pragma unroll
            for (int r = 0; r < 4; ++r)
#pragma unroll
                for (int j = 0; j < 4; ++j) acc[r][j] = fmaf(pr[r], vv[j], acc[r][j]);
        }
        __syncthreads();
    }

#pragma unroll
    for (int r = 0; r < 4; ++r) {
        int row = rg + 16 * r;
        size_t ob = ((size_t)(split * S_ + s) * HW_ + q0 + row) * CE_;
#pragma unroll
        for (int j = 0; j < 4; ++j) Opart[ob + ex + 16 * j + 64 * eb] = acc[r][j];
    }
    if (tid < 64) {
        size_t mb = (size_t)(split * S_ + s) * HW_ + q0 + tid;
        mpart[mb] = mrow[tid];
        lpart[mb] = lrow[tid];
    }
}

// ============================================================================
// Merge NSPLIT partials; out[s][e][q] layout (1,S,ce,h,w)
// ============================================================================
__global__ __launch_bounds__(128)
void cross_combine_kernel(const float* __restrict__ Opart, const float* __restrict__ mpart,
                          const float* __restrict__ lpart, float* __restrict__ out)
{
    const int s = blockIdx.x >> 10;
    const int q = blockIdx.x & 1023;
    const int e = threadIdx.x;
    float m[NSPLIT];
    float M = NEGINF;
#pragma unroll
    for (int i = 0; i < NSPLIT; ++i) {
        m[i] = mpart[(size_t)(i * S_ + s) * HW_ + q];
        M = fmaxf(M, m[i]);
    }
    float L = 0.f, v = 0.f;
#pragma unroll
    for (int i = 0; i < NSPLIT; ++i) {
        float w = expf(m[i] - M);
        L += w * lpart[(size_t)(i * S_ + s) * HW_ + q];
        v += w * Opart[((size_t)(i * S_ + s) * HW_ + q) * CE_ + e];
    }
    out[((size_t)s * CE_ + e) * HW_ + q] = v / L;
}

// ============================================================================
extern "C" void kernel_launch(void* const* d_in, const int* in_sizes, int n_in,
                              void* d_out, int out_size, void* d_ws, size_t ws_size,
                              hipStream_t stream) {
    (void)in_sizes; (void)n_in; (void)out_size; (void)ws_size;
    const float* tgt    = (const float*)d_in[0];
    const float* memory = (const float*)d_in[1];
    const float* pe     = (const float*)d_in[2];
    const float* wsw    = (const float*)d_in[3];
    const float* wsb    = (const float*)d_in[4];
    const float* wcw    = (const float*)d_in[5];
    const float* wcb    = (const float*)d_in[6];
    float* out = (float*)d_out;
    float* W = (float*)d_ws;
    float* Pself = W + O_PSELF;
    float* A     = W + O_A;
    float* Z     = W + O_Z;
    float* Zn    = W + O_ZN;
    float* Qc    = W + O_QC;
    float* Kc    = W + O_KC;
    float* Opart = W + O_OPART;
    float* mpart = W + O_MPART;
    float* lpart = W + O_LPART;

    proj_norm_kernel<<<dim3(16, 4), 256, 0, stream>>>(tgt, wsw, wsb, Pself, HW_);
    self_scores_kernel<<<dim3(16, 16, 4), 256, 0, stream>>>(Pself, A);
    softmax_kernel<<<dim3(4 * HW_), 256, 0, stream>>>(A);
    self_pv_kernel<<<dim3(16, 4, 4), 256, 0, stream>>>(A, tgt, Z);
    inorm_kernel<<<dim3(S_ * C_), 256, 0, stream>>>(Z, Zn);
    proj_norm_kernel<<<dim3(16, 4), 256, 0, stream>>>(Zn, wcw, wcb, Qc, HW_);
    proj_norm_kernel<<<dim3(128, 4), 256, 0, stream>>>(memory, wcw, wcb, Kc, M_);
    cross_flash_kernel<<<dim3(16, NSPLIT, 4), 512, 0, stream>>>(Qc, Kc, pe, Opart, mpart, lpart);
    cross_combine_kernel<<<dim3(S_ * HW_), 128, 0, stream>>>(Opart, mpart, lpart, out);
}

// Round 2
// 429.448 us; speedup vs baseline: 1.6349x; 1.6349x over previous
//
#include <hip/hip_runtime.h>

#define S_ 4
#define C_ 256
#define CE_ 128
#define KD_ 128
#define HW_ 1024
#define T_ 8
#define M_ 8192
#define NSPLIT 8
#define NEGINF -3.0e38f
#define LOG2E 1.4426950408889634f

typedef short bf16x8 __attribute__((ext_vector_type(8)));
typedef float f32x16 __attribute__((ext_vector_type(16)));

#define MFMA32(a, b, c) __builtin_amdgcn_mfma_f32_32x32x16_bf16(a, b, c, 0, 0, 0)

// ---------------- workspace layout (float offsets) ----------------
// Pself : 524288       (dead after self_scores; mpart/lpart overlay)
// A     : 4194304      (dead after self_pv; Opart overlays)
// Z     : 1048576
// Zn    : 1048576
// QF    : 524288 f  (2 MB bf16 hi/lo fragment granules)
// KF    : 4194304 f (16.8 MB)
// VF    : 4194304 f (16.8 MB)
#define O_PSELF 0u
#define O_A     524288u
#define O_Z     4718592u
#define O_ZN    5767168u
#define O_QF    6815744u
#define O_KF    7340032u
#define O_VF    11534336u
// total 15728640 floats = ~62.9 MB
#define O_OPART O_A
#define O_MPART 0u
#define O_LPART 32768u

__device__ __forceinline__ bf16x8 u4_to_b8(uint4 u) {
    union { uint4 u; bf16x8 b; } c; c.u = u; return c.b;
}

__device__ __forceinline__ unsigned cvt_pk_bf16(float a, float b) {
    unsigned r;
    asm("v_cvt_pk_bf16_f32 %0, %1, %2" : "=v"(r) : "v"(a), "v"(b));
    return r;
}

// ============================================================================
// P[s][r][d] = l2norm_d( X[r,s,:] @ W^T + b ) -- row-major output (self path)
// ============================================================================
__global__ __launch_bounds__(256)
void proj_norm_kernel(const float* __restrict__ src, const float* __restrict__ Wm,
                      const float* __restrict__ bias, float* __restrict__ out, int R)
{
    __shared__ float Xs[32][65];
    __shared__ float Ws[32][129];
    const int s  = blockIdx.y;
    const int r0 = blockIdx.x * 64;
    const int t  = r0 >> 10;
    const int l0 = r0 & 1023;
    const int tid = threadIdx.x;
    const int tx = tid & 15, ty = tid >> 4;
    const float* xb = src + ((size_t)(t * S_ + s) * C_) * HW_ + l0;

    float acc[4][8];
#pragma unroll
    for (int i = 0; i < 4; ++i)
#pragma unroll
        for (int j = 0; j < 8; ++j) acc[i][j] = 0.f;

    for (int c0 = 0; c0 < C_; c0 += 32) {
#pragma unroll
        for (int j = 0; j < 8; ++j) {
            int idx = tid + j * 256;
            Xs[idx >> 6][idx & 63] = xb[(size_t)(c0 + (idx >> 6)) * HW_ + (idx & 63)];
        }
#pragma unroll
        for (int j = 0; j < 16; ++j) {
            int idx = tid + j * 256;
            Ws[idx & 31][idx >> 5] = Wm[(idx >> 5) * C_ + c0 + (idx & 31)];
        }
        __syncthreads();
        for (int cc = 0; cc < 32; ++cc) {
            float xv[4], wv[8];
#pragma unroll
            for (int i = 0; i < 4; ++i) xv[i] = Xs[cc][ty * 4 + i];
#pragma unroll
            for (int j = 0; j < 8; ++j) wv[j] = Ws[cc][tx * 8 + j];
#pragma unroll
            for (int i = 0; i < 4; ++i)
#pragma unroll
                for (int j = 0; j < 8; ++j) acc[i][j] = fmaf(xv[i], wv[j], acc[i][j]);
        }
        __syncthreads();
    }

    float bv[8];
#pragma unroll
    for (int j = 0; j < 8; ++j) bv[j] = bias[tx * 8 + j];

#pragma unroll
    for (int i = 0; i < 4; ++i) {
        float ss = 0.f;
#pragma unroll
        for (int j = 0; j < 8; ++j) {
            acc[i][j] += bv[j];
            ss = fmaf(acc[i][j], acc[i][j], ss);
        }
#pragma unroll
        for (int m = 1; m < 16; m <<= 1) ss += __shfl_xor(ss, m);
        float sc = 1.f / fmaxf(sqrtf(ss), 1e-12f);
        int r = r0 + ty * 4 + i;
        float* op = out + ((size_t)s * R + r) * KD_ + tx * 8;
#pragma unroll
        for (int j = 0; j < 8; ++j) op[j] = acc[i][j] * sc;
    }
}

// ============================================================================
// Same GEMM, but writes scaled l2norm output as hi/lo bf16 MFMA fragment
// granules: [s][rb32][hilo][dstep8][lane64*16B], 1 KB per granule.
// Element (r,d): lane=(r&31)|(((d>>3)&1)<<5), byte=(d&7)*2.
// ============================================================================
__global__ __launch_bounds__(256)
void proj_frag_kernel(const float* __restrict__ src, const float* __restrict__ Wm,
                      const float* __restrict__ bias, char* __restrict__ outF,
                      int R, float scale)
{
    __shared__ float Xs[32][65];
    __shared__ float Ws[32][129];
    const int s  = blockIdx.y;
    const int r0 = blockIdx.x * 64;
    const int t  = r0 >> 10;
    const int l0 = r0 & 1023;
    const int tid = threadIdx.x;
    const int tx = tid & 15, ty = tid >> 4;
    const float* xb = src + ((size_t)(t * S_ + s) * C_) * HW_ + l0;

    float acc[4][8];
#pragma unroll
    for (int i = 0; i < 4; ++i)
#pragma unroll
        for (int j = 0; j < 8; ++j) acc[i][j] = 0.f;

    for (int c0 = 0; c0 < C_; c0 += 32) {
#pragma unroll
        for (int j = 0; j < 8; ++j) {
            int idx = tid + j * 256;
            Xs[idx >> 6][idx & 63] = xb[(size_t)(c0 + (idx >> 6)) * HW_ + (idx & 63)];
        }
#pragma unroll
        for (int j = 0; j < 16; ++j) {
            int idx = tid + j * 256;
            Ws[idx & 31][idx >> 5] = Wm[(idx >> 5) * C_ + c0 + (idx & 31)];
        }
        __syncthreads();
        for (int cc = 0; cc < 32; ++cc) {
            float xv[4], wv[8];
#pragma unroll
            for (int i = 0; i < 4; ++i) xv[i] = Xs[cc][ty * 4 + i];
#pragma unroll
            for (int j = 0; j < 8; ++j) wv[j] = Ws[cc][tx * 8 + j];
#pragma unroll
            for (int i = 0; i < 4; ++i)
#pragma unroll
                for (int j = 0; j < 8; ++j) acc[i][j] = fmaf(xv[i], wv[j], acc[i][j]);
        }
        __syncthreads();
    }

    float bv[8];
#pragma unroll
    for (int j = 0; j < 8; ++j) bv[j] = bias[tx * 8 + j];

    const int RB = R >> 5;
#pragma unroll
    for (int i = 0; i < 4; ++i) {
        float ss = 0.f;
#pragma unroll
        for (int j = 0; j < 8; ++j) {
            acc[i][j] += bv[j];
            ss = fmaf(acc[i][j], acc[i][j], ss);
        }
#pragma unroll
        for (int m = 1; m < 16; m <<= 1) ss += __shfl_xor(ss, m);
        float sc = scale / fmaxf(sqrtf(ss), 1e-12f);
        int r = r0 + ty * 4 + i;
        float v[8];
#pragma unroll
        for (int j = 0; j < 8; ++j) v[j] = acc[i][j] * sc;
        unsigned hp[4], lp[4];
#pragma unroll
        for (int p = 0; p < 4; ++p) {
            hp[p] = cvt_pk_bf16(v[2 * p], v[2 * p + 1]);
            float f0 = __uint_as_float(hp[p] << 16);
            float f1 = __uint_as_float(hp[p] & 0xffff0000u);
            lp[p] = cvt_pk_bf16(v[2 * p] - f0, v[2 * p + 1] - f1);
        }
        int lane = (r & 31) | ((tx & 1) << 5);
        int ds = tx >> 1;
        size_t gb = ((((size_t)s * RB + (r >> 5)) * 2 + 0) * 8 + ds) * 1024 + (size_t)lane * 16;
        *(uint4*)(outF + gb) = make_uint4(hp[0], hp[1], hp[2], hp[3]);
        *(uint4*)(outF + gb + 8 * 1024) = make_uint4(lp[0], lp[1], lp[2], lp[3]);
    }
}

// ============================================================================
// pe (T,S,128e,1024l) -> V fragment granules [s][kb16][hilo][etile4][1KB]
// Element (k,e): lane=(e&31)|(((k>>3)&1)<<5), byte=(k&7)*2.
// ============================================================================
__global__ __launch_bounds__(256)
void vconv_kernel(const float* __restrict__ pe, char* __restrict__ VF)
{
    int gid = blockIdx.x * 256 + threadIdx.x;   // 2^19 threads
    int lg = gid & 127;
    int e  = (gid >> 7) & 127;
    int s  = (gid >> 14) & 3;
    int t  = gid >> 16;
    int l0 = lg * 8;
    const float* p = pe + (((size_t)(t * S_ + s) * CE_ + e) * HW_ + l0);
    float4 va = ((const float4*)p)[0];
    float4 vb = ((const float4*)p)[1];
    float v[8] = {va.x, va.y, va.z, va.w, vb.x, vb.y, vb.z, vb.w};
    unsigned hp[4], lp[4];
#pragma unroll
    for (int q = 0; q < 4; ++q) {
        hp[q] = cvt_pk_bf16(v[2 * q], v[2 * q + 1]);
        float f0 = __uint_as_float(hp[q] << 16);
        float f1 = __uint_as_float(hp[q] & 0xffff0000u);
        lp[q] = cvt_pk_bf16(v[2 * q] - f0, v[2 * q + 1] - f1);
    }
    int k = t * 1024 + l0;
    int kb16 = k >> 4;
    int lane = (e & 31) | (((l0 >> 3) & 1) << 5);
    int et = e >> 5;
    size_t gb = ((((size_t)s * 512 + kb16) * 2 + 0) * 4 + et) * 1024 + (size_t)lane * 16;
    *(uint4*)(VF + gb) = make_uint4(hp[0], hp[1], hp[2], hp[3]);
    *(uint4*)(VF + gb + 4 * 1024) = make_uint4(lp[0], lp[1], lp[2], lp[3]);
}

// ============================================================================
// A[s][q][k] = 30 * dot128(P[s][q], P[s][k])   (self path, unchanged)
// ============================================================================
__global__ __launch_bounds__(256)
void self_scores_kernel(const float* __restrict__ P, float* __restrict__ A)
{
    __shared__ float Qs[64][33];
    __shared__ float Ks[64][33];
    const int s = blockIdx.z;
    const int q0 = blockIdx.x * 64, k0 = blockIdx.y * 64;
    const int tid = threadIdx.x;
    const int tx = tid & 15, ty = tid >> 4;
    const float* Pb = P + (size_t)s * HW_ * KD_;

    float acc[4][4];
#pragma unroll
    for (int i = 0; i < 4; ++i)
#pragma unroll
        for (int j = 0; j < 4; ++j) acc[i][j] = 0.f;

    for (int d0 = 0; d0 < KD_; d0 += 32) {
#pragma unroll
        for (int j = 0; j < 8; ++j) {
            int idx = tid + j * 256;
            int r = idx >> 5, dd = idx & 31;
            Qs[r][dd] = Pb[(size_t)(q0 + r) * KD_ + d0 + dd];
            Ks[r][dd] = Pb[(size_t)(k0 + r) * KD_ + d0 + dd];
        }
        __syncthreads();
        for (int dd = 0; dd < 32; ++dd) {
            float qv[4], kv[4];
#pragma unroll
            for (int i = 0; i < 4; ++i) qv[i] = Qs[ty * 4 + i][dd];
#pragma unroll
            for (int j = 0; j < 4; ++j) kv[j] = Ks[tx * 4 + j][dd];
#pragma unroll
            for (int i = 0; i < 4; ++i)
#pragma unroll
                for (int j = 0; j < 4; ++j) acc[i][j] = fmaf(qv[i], kv[j], acc[i][j]);
        }
        __syncthreads();
    }
#pragma unroll
    for (int i = 0; i < 4; ++i)
#pragma unroll
        for (int j = 0; j < 4; ++j)
            A[((size_t)s * HW_ + q0 + ty * 4 + i) * HW_ + k0 + tx * 4 + j] = acc[i][j] * 30.0f;
}

// ============================================================================
__global__ __launch_bounds__(256)
void softmax_kernel(float* __restrict__ A)
{
    __shared__ float red[4];
    __shared__ float red2[4];
    float* p = A + (size_t)blockIdx.x * HW_;
    const int tid = threadIdx.x;
    float4 x = ((float4*)p)[tid];
    float mx = fmaxf(fmaxf(x.x, x.y), fmaxf(x.z, x.w));
#pragma unroll
    for (int m = 1; m < 64; m <<= 1) mx = fmaxf(mx, __shfl_xor(mx, m));
    if ((tid & 63) == 0) red[tid >> 6] = mx;
    __syncthreads();
    mx = fmaxf(fmaxf(red[0], red[1]), fmaxf(red[2], red[3]));
    x.x = expf(x.x - mx); x.y = expf(x.y - mx);
    x.z = expf(x.z - mx); x.w = expf(x.w - mx);
    float sm = x.x + x.y + x.z + x.w;
#pragma unroll
    for (int m = 1; m < 64; m <<= 1) sm += __shfl_xor(sm, m);
    if ((tid & 63) == 0) red2[tid >> 6] = sm;
    __syncthreads();
    sm = red2[0] + red2[1] + red2[2] + red2[3];
    float inv = 1.f / sm;
    x.x *= inv; x.y *= inv; x.z *= inv; x.w *= inv;
    ((float4*)p)[tid] = x;
}

// ============================================================================
__global__ __launch_bounds__(256)
void self_pv_kernel(const float* __restrict__ A, const float* __restrict__ X,
                    float* __restrict__ Z)
{
    __shared__ float As[64][33];
    __shared__ float Vs[32][65];
    const int s = blockIdx.z;
    const int q0 = blockIdx.x * 64;
    const int c0 = blockIdx.y * 64;
    const int tid = threadIdx.x;
    const int tx = tid & 15, ty = tid >> 4;
    const float* Ab = A + (size_t)s * HW_ * HW_;
    const float* Xb = X + (size_t)s * C_ * HW_;

    float acc[4][4];
#pragma unroll
    for (int i = 0; i < 4; ++i)
#pragma unroll
        for (int j = 0; j < 4; ++j) acc[i][j] = 0.f;

    for (int k0 = 0; k0 < HW_; k0 += 32) {
#pragma unroll
        for (int j = 0; j < 8; ++j) {
            int idx = tid + j * 256;
            int r = idx >> 5, kk = idx & 31;
            As[r][kk] = Ab[(size_t)(q0 + r) * HW_ + k0 + kk];
        }
#pragma unroll
        for (int j = 0; j < 8; ++j) {
            int idx = tid + j * 256;
            int ch = idx >> 5, kk = idx & 31;
            Vs[kk][ch] = Xb[(size_t)(c0 + ch) * HW_ + k0 + kk];
        }
        __syncthreads();
        for (int kk = 0; kk < 32; ++kk) {
            float av[4], vv[4];
#pragma unroll
            for (int i = 0; i < 4; ++i) av[i] = As[ty * 4 + i][kk];
#pragma unroll
            for (int j = 0; j < 4; ++j) vv[j] = Vs[kk][tx * 4 + j];
#pragma unroll
            for (int i = 0; i < 4; ++i)
#pragma unroll
                for (int j = 0; j < 4; ++j) acc[i][j] = fmaf(av[i], vv[j], acc[i][j]);
        }
        __syncthreads();
    }
#pragma unroll
    for (int i = 0; i < 4; ++i)
#pragma unroll
        for (int j = 0; j < 4; ++j) {
            int q = q0 + ty * 4 + i, ch = c0 + tx * 4 + j;
            size_t a = (size_t)(s * C_ + ch) * HW_ + q;
            Z[a] = acc[i][j] + X[a];
        }
}

// ============================================================================
__global__ __launch_bounds__(256)
void inorm_kernel(const float* __restrict__ Z, float* __restrict__ Zn)
{
    __shared__ float red[4];
    __shared__ float red2[4];
    const float* p = Z + (size_t)blockIdx.x * HW_;
    float* q = Zn + (size_t)blockIdx.x * HW_;
    const int tid = threadIdx.x;
    float4 x = ((const float4*)p)[tid];
    float sm = x.x + x.y + x.z + x.w;
#pragma unroll
    for (int m = 1; m < 64; m <<= 1) sm += __shfl_xor(sm, m);
    if ((tid & 63) == 0) red[tid >> 6] = sm;
    __syncthreads();
    float mu = (red[0] + red[1] + red[2] + red[3]) * (1.f / 1024.f);
    float dx0 = x.x - mu, dx1 = x.y - mu, dx2 = x.z - mu, dx3 = x.w - mu;
    float ss = dx0 * dx0 + dx1 * dx1 + dx2 * dx2 + dx3 * dx3;
#pragma unroll
    for (int m = 1; m < 64; m <<= 1) ss += __shfl_xor(ss, m);
    if ((tid & 63) == 0) red2[tid >> 6] = ss;
    __syncthreads();
    float var = (red2[0] + red2[1] + red2[2] + red2[3]) * (1.f / 1024.f);
    float inv = 1.f / sqrtf(var + 1e-5f);
    float4 o;
    o.x = dx0 * inv; o.y = dx1 * inv; o.z = dx2 * inv; o.w = dx3 * inv;
    ((float4*)q)[tid] = o;
}

// ============================================================================
// MFMA flash cross-attention. Swapped QK^T (D = S^T: col=lane&31=q).
// Split-bf16 (hi+lo) on Q,K,P,V: 3 MFMAs per logical fp32 product.
// Grid (qt 8, split 8, s 4), 256 threads = 4 waves, each wave owns 32 q rows.
// LDS: double-buffered 2 x 64KB of K/V fragment granules (1KB each).
// ============================================================================
__global__ __launch_bounds__(256, 1)
void cross_flash_mfma(const char* __restrict__ QF, const char* __restrict__ KF,
                      const char* __restrict__ VF, float* __restrict__ Opart,
                      float* __restrict__ mpart, float* __restrict__ lpart)
{
    __shared__ __align__(16) char lds[2][65536];
    const int qt = blockIdx.x, split = blockIdx.y, s = blockIdx.z;
    const int tid = threadIdx.x;
    const int wv = tid >> 6, lane = tid & 63;
    const int l31 = lane & 31;
    const bool hh = lane >= 32;
    const int qb32 = qt * 4 + wv;

    // Q fragments (B operand): resident in registers
    uint4 QH[8], QL[8];
    {
        const char* qb = QF + (((size_t)s * 32 + qb32) * 2) * 8192;
#pragma unroll
        for (int ds = 0; ds < 8; ++ds) {
            QH[ds] = *(const uint4*)(qb + ds * 1024 + lane * 16);
            QL[ds] = *(const uint4*)(qb + 8192 + ds * 1024 + lane * 16);
        }
    }

    f32x16 O[4];
#pragma unroll
    for (int et = 0; et < 4; ++et)
#pragma unroll
        for (int i = 0; i < 16; ++i) O[et][i] = 0.f;
    float m = NEGINF, lsum = 0.f;

    const int k0base = split * 1024;

    auto STAGE = [&](int b, int kt) {
        int k0 = k0base + kt * 64;
#pragma unroll
        for (int i = 0; i < 16; ++i) {
            int g = wv * 16 + i;
            const char* src;
            if (g < 32) {
                int at = g >> 4, hl = (g >> 3) & 1, ds = g & 7;
                src = KF + ((((size_t)s * 256 + (k0 >> 5) + at) * 2 + hl) * 8 + ds) * 1024
                         + (size_t)lane * 16;
            } else {
                int g2 = g - 32, ks = g2 >> 3, hl = (g2 >> 2) & 1, et = g2 & 3;
                src = VF + ((((size_t)s * 512 + (k0 >> 4) + ks) * 2 + hl) * 4 + et) * 1024
                         + (size_t)lane * 16;
            }
            char* dst = &lds[b][g * 1024];
            __builtin_amdgcn_global_load_lds(
                (const __attribute__((address_space(1))) void*)src,
                (__attribute__((address_space(3))) void*)dst, 16, 0, 0);
        }
    };

    STAGE(0, 0);
    __syncthreads();

    for (int kt = 0; kt < 16; ++kt) {
        const int b = kt & 1;
        if (kt < 15) STAGE(b ^ 1, kt + 1);
        const char* Bp = lds[b];

        // ---- scores: D = K * Q^T (32 keys x 32 q per atile) ----
        f32x16 a0, a1;
#pragma unroll
        for (int i = 0; i < 16; ++i) { a0[i] = 0.f; a1[i] = 0.f; }
#pragma unroll
        for (int ds = 0; ds < 8; ++ds) {
            bf16x8 kh0 = *(const bf16x8*)(Bp + (0 + ds) * 1024 + lane * 16);
            bf16x8 kl0 = *(const bf16x8*)(Bp + (8 + ds) * 1024 + lane * 16);
            bf16x8 kh1 = *(const bf16x8*)(Bp + (16 + ds) * 1024 + lane * 16);
            bf16x8 kl1 = *(const bf16x8*)(Bp + (24 + ds) * 1024 + lane * 16);
            bf16x8 qh = u4_to_b8(QH[ds]), ql = u4_to_b8(QL[ds]);
            a0 = MFMA32(kh0, qh, a0);
            a0 = MFMA32(kh0, ql, a0);
            a0 = MFMA32(kl0, qh, a0);
            a1 = MFMA32(kh1, qh, a1);
            a1 = MFMA32(kh1, ql, a1);
            a1 = MFMA32(kl1, qh, a1);
        }

        // ---- online softmax (row q = lane&31, lane-local) ----
        float tmax = NEGINF;
#pragma unroll
        for (int i = 0; i < 16; ++i) tmax = fmaxf(tmax, fmaxf(a0[i], a1[i]));
        tmax = fmaxf(tmax, __shfl_xor(tmax, 32));
        float mnew = fmaxf(m, tmax);
        float alpha = exp2f((m - mnew) * LOG2E);
        float mn2 = mnew * LOG2E;
        float P[32];
        float tsum = 0.f;
#pragma unroll
        for (int i = 0; i < 16; ++i) { P[i] = exp2f(fmaf(a0[i], LOG2E, -mn2)); tsum += P[i]; }
#pragma unroll
        for (int i = 0; i < 16; ++i) { P[16 + i] = exp2f(fmaf(a1[i], LOG2E, -mn2)); tsum += P[16 + i]; }
        tsum += __shfl_xor(tsum, 32);
        lsum = lsum * alpha + tsum;
        m = mnew;

        // rescale O: alpha lives at lane q, O rows are reg-mapped
#pragma unroll
        for (int r = 0; r < 16; ++r) {
            int qrow = (r & 3) + 8 * (r >> 2) + (hh ? 4 : 0);
            float ar = __shfl(alpha, qrow | (hh ? 32 : 0));
#pragma unroll
            for (int et = 0; et < 4; ++et) O[et][r] *= ar;
        }

        // ---- pack P into hi/lo bf16 pairs ----
        unsigned hpk[16], lpk[16];
#pragma unroll
        for (int p = 0; p < 16; ++p) {
            hpk[p] = cvt_pk_bf16(P[2 * p], P[2 * p + 1]);
            float f0 = __uint_as_float(hpk[p] << 16);
            float f1 = __uint_as_float(hpk[p] & 0xffff0000u);
            lpk[p] = cvt_pk_bf16(P[2 * p] - f0, P[2 * p + 1] - f1);
        }

        // ---- PV: O[q][e] += P[q][k] * V[k][e] ----
#pragma unroll
        for (int ks = 0; ks < 4; ++ks) {
            const int i0 = (ks >> 1) * 8 + (ks & 1) * 4;
            unsigned t0 = hh ? hpk[i0 + 2] : hpk[i0];
            unsigned u0 = hh ? hpk[i0] : hpk[i0 + 2];
            unsigned w0 = __shfl_xor(u0, 32);
            unsigned A0 = hh ? w0 : t0;
            unsigned A2 = hh ? t0 : w0;
            unsigned t1 = hh ? hpk[i0 + 3] : hpk[i0 + 1];
            unsigned u1 = hh ? hpk[i0 + 1] : hpk[i0 + 3];
            unsigned w1 = __shfl_xor(u1, 32);
            unsigned A1 = hh ? w1 : t1;
            unsigned A3 = hh ? t1 : w1;

            unsigned s0 = hh ? lpk[i0 + 2] : lpk[i0];
            unsigned v0 = hh ? lpk[i0] : lpk[i0 + 2];
            unsigned x0 = __shfl_xor(v0, 32);
            unsigned B0 = hh ? x0 : s0;
            unsigned B2 = hh ? s0 : x0;
            unsigned s1 = hh ? lpk[i0 + 3] : lpk[i0 + 1];
            unsigned v1 = hh ? lpk[i0 + 1] : lpk[i0 + 3];
            unsigned x1 = __shfl_xor(v1, 32);
            unsigned B1 = hh ? x1 : s1;
            unsigned B3 = hh ? s1 : x1;

            bf16x8 pa_hi = u4_to_b8(make_uint4(A0, A1, A2, A3));
            bf16x8 pa_lo = u4_to_b8(make_uint4(B0, B1, B2, B3));
#pragma unroll
            for (int et = 0; et < 4; ++et) {
                bf16x8 vh = *(const bf16x8*)(Bp + (32 + (ks * 2 + 0) * 4 + et) * 1024 + lane * 16);
                bf16x8 vl = *(const bf16x8*)(Bp + (32 + (ks * 2 + 1) * 4 + et) * 1024 + lane * 16);
                O[et] = MFMA32(pa_hi, vh, O[et]);
                O[et] = MFMA32(pa_hi, vl, O[et]);
                O[et] = MFMA32(pa_lo, vh, O[et]);
            }
        }
        __syncthreads();
    }

    // ---- epilogue: unnormalized O + m/l stats ----
    size_t ob = ((size_t)(split * S_ + s) * HW_ + qt * 128 + wv * 32) * CE_;
#pragma unroll
    for (int r = 0; r < 16; ++r) {
        int qrow = (r & 3) + 8 * (r >> 2) + (hh ? 4 : 0);
#pragma unroll
        for (int et = 0; et < 4; ++et)
            Opart[ob + (size_t)qrow * CE_ + et * 32 + l31] = O[et][r];
    }
    if (lane < 32) {
        size_t mb = (size_t)(split * S_ + s) * HW_ + qt * 128 + wv * 32 + lane;
        mpart[mb] = m;
        lpart[mb] = lsum;
    }
}

// ============================================================================
// Merge NSPLIT partials; out[s][e][q] layout (1,S,ce,h,w)
// ============================================================================
__global__ __launch_bounds__(128)
void cross_combine_kernel(const float* __restrict__ Opart, const float* __restrict__ mpart,
                          const float* __restrict__ lpart, float* __restrict__ out)
{
    const int s = blockIdx.x >> 10;
    const int q = blockIdx.x & 1023;
    const int e = threadIdx.x;
    float m[NSPLIT];
    float M = NEGINF;
#pragma unroll
    for (int i = 0; i < NSPLIT; ++i) {
        m[i] = mpart[(size_t)(i * S_ + s) * HW_ + q];
        M = fmaxf(M, m[i]);
    }
    float L = 0.f, v = 0.f;
#pragma unroll
    for (int i = 0; i < NSPLIT; ++i) {
        float w = expf(m[i] - M);
        L += w * lpart[(size_t)(i * S_ + s) * HW_ + q];
        v += w * Opart[((size_t)(i * S_ + s) * HW_ + q) * CE_ + e];
    }
    out[((size_t)s * CE_ + e) * HW_ + q] = v / L;
}

// ============================================================================
extern "C" void kernel_launch(void* const* d_in, const int* in_sizes, int n_in,
                              void* d_out, int out_size, void* d_ws, size_t ws_size,
                              hipStream_t stream) {
    (void)in_sizes; (void)n_in; (void)out_size; (void)ws_size;
    const float* tgt    = (const float*)d_in[0];
    const float* memory = (const float*)d_in[1];
    const float* pe     = (const float*)d_in[2];
    const float* wsw    = (const float*)d_in[3];
    const float* wsb    = (const float*)d_in[4];
    const float* wcw    = (const float*)d_in[5];
    const float* wcb    = (const float*)d_in[6];
    float* out = (float*)d_out;
    float* W = (float*)d_ws;
    float* Pself = W + O_PSELF;
    float* A     = W + O_A;
    float* Z     = W + O_Z;
    float* Zn    = W + O_ZN;
    char*  QFc   = (char*)(W + O_QF);
    char*  KFc   = (char*)(W + O_KF);
    char*  VFc   = (char*)(W + O_VF);
    float* Opart = W + O_OPART;   // overlays A (dead after self_pv)
    float* mpart = W + O_MPART;   // overlays Pself (dead after self_scores)
    float* lpart = W + O_LPART;

    proj_norm_kernel<<<dim3(16, 4), 256, 0, stream>>>(tgt, wsw, wsb, Pself, HW_);
    self_scores_kernel<<<dim3(16, 16, 4), 256, 0, stream>>>(Pself, A);
    softmax_kernel<<<dim3(4 * HW_), 256, 0, stream>>>(A);
    self_pv_kernel<<<dim3(16, 4, 4), 256, 0, stream>>>(A, tgt, Z);
    inorm_kernel<<<dim3(S_ * C_), 256, 0, stream>>>(Z, Zn);
    proj_frag_kernel<<<dim3(16, 4), 256, 0, stream>>>(Zn, wcw, wcb, QFc, HW_, 30.0f);
    proj_frag_kernel<<<dim3(128, 4), 256, 0, stream>>>(memory, wcw, wcb, KFc, M_, 1.0f);
    vconv_kernel<<<dim3(2048), 256, 0, stream>>>(pe, VFc);
    cross_flash_mfma<<<dim3(8, NSPLIT, 4), 256, 0, stream>>>(QFc, KFc, VFc, Opart, mpart, lpart);
    cross_combine_kernel<<<dim3(S_ * HW_), 128, 0, stream>>>(Opart, mpart, lpart, out);
}